// Round 11
// baseline (1198.771 us; speedup 1.0000x reference)
//
#include <hip/hip_runtime.h>
#include <math.h>

// DNC: B=32,T=64,I=64,O=64,H=512,N=128,W=64,IF=198
// R24 = R23 (best, 797us) + P2 link-work moved off the itf-critical path:
//  - phase 1: while polling itf, precompute per-thread sums A,B,A2,B2,P,Q
//    from step-(t-1) state (L/LT regs, rw, alloc, prec). wgag (the only
//    itf-dependent factor in the link recurrence) is a SCALAR, so post-itf
//    bwp/fwp are O(1) closed forms.
//  - phase 3: bwp = A(1-wwm) - wgag*B + wwm*(P-diag); fwp analogous.
//    The 64-MAC link loop is GONE from the on-chain phase.
//  - phase 6: deferred L/LT register-state update (off-chain, after rvec
//    publish). PREC and ALLOC parity-double-buffered so old state stays
//    readable while new state is written.
#define Bb 32
#define Tt 64
#define Ii 64
#define Oo 64
#define Hh 512
#define Nn 128
#define Wd 64
#define IFs 198
#define KV 640
#define G4 2048

#define NP1 128          /* 16 bb-groups x 8 jb-slices */
#define NWG 160          /* + 32 P2 wgs */
#define NT 512

// ---- LDS layout (float offsets). P1/P2 blocks overlap (roles fixed per wg).
// P2 block:
#define P2_MEM    0        /* 128*65 = 8320 */
#define P2_H      8320     /* 576 [h|rvec] */
#define P2_SCR    8896     /* 2048 */
#define P2_ITF    10944    /* 224 */
#define P2_ERASE  11168
#define P2_WVEC   11232
#define P2_USAGE  11296
#define P2_RW     11552
#define P2_WW     11680
#define P2_SCAN   11808
#define P2_SS     11936
#define P2_SCAL   12064    /* 16 */
#define P2_BIF    12080    /* 224 */
#define P2_ALLOC  12304    /* 2 x 128 parity */
#define P2_PREC   12560    /* 2 x 128 parity */
// P1 block (W_if rows padded to 68):
#define P1_WIF    0        /* 198*68 = 13464 */
#define P1_BS     13464    /* 256 */
#define P1_V      13720    /* 640 rows x 2 batches interleaved = 1280 */
#define P1_CC     15016    /* 128 */
#define P1_HSL    15144    /* 128 */
#define P1_PACC   15272    /* 32*65 float4 = 8320 */
#define SMEM_FLOATS 23592  /* 94368 B */
#define SMEM_BYTES (SMEM_FLOATS * 4)

#define S_WWSUM 0

// WT row permutation: rows = [h(512) | x(64) | rvec(64)].
__device__ __align__(16) float g_WT[KV * G4];
__device__ __align__(16) float g_bsum[G4];
typedef unsigned long long u64;
// Tagged handoffs: u64 = (step_tag << 32) | float_bits. Relaxed agent atomics.
__device__ u64 g_h64[2 * Bb * Hh];   // h, step-parity double buffer, tag t+1
__device__ u64 g_rv64[Bb * Wd];      // rvec(t) tag t+1
__device__ u64 g_if64[Bb * 8 * 200]; // itf partials [b][jb(8)][o pad200] tag t+1

__device__ __forceinline__ float sigf(float v) { return 1.f / (1.f + expf(-v)); }

__device__ __forceinline__ u64 ldrelax(const u64* p) {
  return __hip_atomic_load(p, __ATOMIC_RELAXED, __HIP_MEMORY_SCOPE_AGENT);
}
__device__ __forceinline__ void tstore(u64* p, unsigned tag, float v) {
  u64 val = ((u64)tag << 32) | (u64)__float_as_uint(v);
  __hip_atomic_store(p, val, __ATOMIC_RELAXED, __HIP_MEMORY_SCOPE_AGENT);
}
__device__ __forceinline__ float tval(u64 v) {
  return __uint_as_float((unsigned)(v & 0xffffffffu));
}
// Staged-backoff sleep (R23-proven): 2 fast retries, then long sleep.
__device__ __forceinline__ void bsleep(int k) {
  if (k < 2) __builtin_amdgcn_s_sleep(1);
  else       __builtin_amdgcn_s_sleep(8);
}
// Combined concurrent polls (R19): reload ALL invalid slots per iteration.
__device__ __forceinline__ void waitpair(const u64* p0, const u64* p1,
                                         u64& v0, u64& v1, unsigned tag) {
  int k = 0;
  while (((unsigned)(v0 >> 32)) != tag || ((unsigned)(v1 >> 32)) != tag) {
    bsleep(k); ++k;
    v0 = ldrelax(p0);
    v1 = ldrelax(p1);
  }
}
__device__ __forceinline__ void waitquad(const u64* p0, const u64* p1,
                                         const u64* p2, const u64* p3,
                                         u64& v0, u64& v1, u64& v2, u64& v3,
                                         unsigned tag) {
  int k = 0;
  while (((unsigned)(v0 >> 32)) != tag || ((unsigned)(v1 >> 32)) != tag ||
         ((unsigned)(v2 >> 32)) != tag || ((unsigned)(v3 >> 32)) != tag) {
    bsleep(k); ++k;
    v0 = ldrelax(p0);
    v1 = ldrelax(p1);
    v2 = ldrelax(p2);
    v3 = ldrelax(p3);
  }
}

#define TIN 512
__global__ __launch_bounds__(TIN) void dnc_init(const float* __restrict__ W_ih,
                                                const float* __restrict__ W_hh,
                                                const float* __restrict__ b_ih,
                                                const float* __restrict__ b_hh) {
  __shared__ float tile[64][65];
  const int tid = threadIdx.x;
  int i0 = blockIdx.x * blockDim.x + tid;
  int st = gridDim.x * blockDim.x;
  for (int idx = i0; idx < G4; idx += st) g_bsum[idx] = b_ih[idx] + b_hh[idx];
  for (int idx = i0; idx < 2 * Bb * Hh; idx += st) g_h64[idx] = 0ull;
  for (int idx = i0; idx < Bb * Wd; idx += st) g_rv64[idx] = 0ull;
  for (int idx = i0; idx < Bb * 8 * 200; idx += st) g_if64[idx] = 0ull;

  for (int tileId = blockIdx.x; tileId < 320; tileId += gridDim.x) {
    int tc = tileId >> 5, tj = tileId & 31;
    for (int k = tid; k < 64 * 64; k += TIN) {
      int r = k >> 6, cl = k & 63;
      int j = tj * 64 + r, c = tc * 64 + cl;
      tile[r][cl] = (c < 128) ? W_ih[j * 128 + c] : W_hh[j * 512 + (c - 128)];
    }
    __syncthreads();
    for (int k = tid; k < 64 * 64; k += TIN) {
      int cl = k >> 6, rjj = k & 63;
      int c = tc * 64 + cl;
      // rows: h u -> u ; x c -> 512+c ; rvec -> 576+(c-64)  (== 512+c)
      int rp = (c < 128) ? (512 + c) : (c - 128);
      g_WT[(size_t)rp * G4 + tj * 64 + rjj] = tile[rjj][cl];
    }
    __syncthreads();
  }
}

__global__ __launch_bounds__(NT) void dnc_main(const float* __restrict__ x,
                                               const float* __restrict__ W_if,
                                               const float* __restrict__ b_if,
                                               const float* __restrict__ W_out,
                                               const float* __restrict__ b_out,
                                               float* __restrict__ out) {
  extern __shared__ float sm[];
  const int tid = threadIdx.x;
  const int wg = blockIdx.x;

  if (wg < NP1) {
    // ======================= P1: gates GEMV + fused LSTM + itf partials
    // (verbatim R23 — untouched)
    const int jb = wg & 7;
    const int bb = wg >> 3;
    const int b0 = bb * 2;
    for (int i = tid; i < IFs * 64; i += NT) {
      int o = i >> 6, c = i & 63;
      sm[P1_WIF + o * 68 + c] = W_if[(size_t)o * Hh + jb * 64 + c];
    }
    if (tid < 64) {
      int gq = tid >> 4, m = tid & 15;
      ((float4*)(sm + P1_BS))[tid] = ((const float4*)g_bsum)[gq * 128 + jb * 16 + m];
    }
    if (tid < 128) sm[P1_CC + tid] = 0.f;
    __syncthreads();

    for (int t = 0; t < Tt; ++t) {
      {  // stage h(t-1) + x, batch-interleaved [row][bl] — concurrent wait
        const u64* hsrc = g_h64 + (size_t)((t + 1) & 1) * (Bb * Hh);
        const int u = tid;
        const u64* a0 = hsrc + (size_t)b0 * Hh + u;
        const u64* a1 = hsrc + (size_t)(b0 + 1) * Hh + u;
        u64 v0 = ldrelax(a0), v1 = ldrelax(a1);
        waitpair(a0, a1, v0, v1, (unsigned)t);
        float2 hh;
        hh.x = tval(v0);
        hh.y = tval(v1);
        *(float2*)(sm + P1_V + u * 2) = hh;
        if (tid < 128) {
          const int bl2 = tid >> 6, i = tid & 63;
          float xv = x[((size_t)(b0 + bl2) * Tt + t) * Ii + i];
          sm[P1_V + (512 + i) * 2 + bl2] = xv;
        }
      }
      __syncthreads();

      {  // GEMV: 640 rows split 16 ways; each weight loaded once.
        const int fg = tid & 31, ks = tid >> 5;  // ks 0..15, rows ks*40..+39
        const int fcolA = ((fg >> 4) * 128) + jb * 16 + (fg & 15);  // gates 0,1
        const float* v2 = sm + P1_V + ks * 80;
        const float4* wpA = (const float4*)g_WT + (size_t)(ks * 40) * 512 + fcolA;
        if (ks >= 14) {  // wave 7 owns rvec rows 576..639 — concurrent wait
          const int j = tid & 63;
          const u64* r0 = g_rv64 + (size_t)b0 * Wd + j;
          const u64* r1 = g_rv64 + (size_t)(b0 + 1) * Wd + j;
          u64 u0 = ldrelax(r0), u1 = ldrelax(r1);
          waitpair(r0, r1, u0, u1, (unsigned)t);
          float2 rv;
          rv.x = tval(u0);
          rv.y = tval(u1);
          *(float2*)(sm + P1_V + (576 + j) * 2) = rv;  // same-wave write->read
        }
        float4 aA0 = {0.f, 0.f, 0.f, 0.f}, aA1 = {0.f, 0.f, 0.f, 0.f};
        float4 aB0 = {0.f, 0.f, 0.f, 0.f}, aB1 = {0.f, 0.f, 0.f, 0.f};
#pragma unroll 4
        for (int r = 0; r < 40; ++r) {
          float4 wA = wpA[(size_t)r * 512];
          float4 wB = wpA[(size_t)r * 512 + 256];      // gates 2,3
          float2 vv = *(const float2*)(v2 + r * 2);
          aA0.x += wA.x * vv.x; aA0.y += wA.y * vv.x; aA0.z += wA.z * vv.x; aA0.w += wA.w * vv.x;
          aA1.x += wA.x * vv.y; aA1.y += wA.y * vv.y; aA1.z += wA.z * vv.y; aA1.w += wA.w * vv.y;
          aB0.x += wB.x * vv.x; aB0.y += wB.y * vv.x; aB0.z += wB.z * vv.x; aB0.w += wB.w * vv.x;
          aB1.x += wB.x * vv.y; aB1.y += wB.y * vv.y; aB1.z += wB.z * vv.y; aB1.w += wB.w * vv.y;
        }
        float4* pacc = (float4*)(sm + P1_PACC);
        pacc[(ks * 2 + 0) * 65 + fg] = aA0;
        pacc[(ks * 2 + 1) * 65 + fg] = aA1;
        pacc[(ks * 2 + 0) * 65 + fg + 32] = aB0;
        pacc[(ks * 2 + 1) * 65 + fg + 32] = aB1;
      }
      __syncthreads();
      if (tid < 128) {  // fused K-reduce (16 partials) + LSTM; h published tagged
        const int bl = tid >> 6, l = tid & 63;
        const float* pb = sm + P1_PACC + bl * 260 + l;
        float gv0 = 0.f, gv1 = 0.f, gv2 = 0.f, gv3 = 0.f;
#pragma unroll
        for (int ks = 0; ks < 16; ++ks) {
          const float* pk = pb + ks * 520;
          gv0 += pk[0];
          gv1 += pk[64];
          gv2 += pk[128];
          gv3 += pk[192];
        }
        float ig = gv0 + sm[P1_BS + l];
        float fg = gv1 + sm[P1_BS + 64 + l];
        float gg = gv2 + sm[P1_BS + 128 + l];
        float og = gv3 + sm[P1_BS + 192 + l];
        float co = sm[P1_CC + bl * 64 + l];
        float cn = sigf(fg) * co + sigf(ig) * tanhf(gg);
        float hn = sigf(og) * tanhf(cn);
        sm[P1_CC + bl * 64 + l] = cn;
        sm[P1_HSL + bl * 64 + l] = hn;
        tstore(g_h64 + (size_t)(t & 1) * (Bb * Hh) + (size_t)(b0 + bl) * Hh + jb * 64 + l,
               (unsigned)(t + 1), hn);
      }
      __syncthreads();
      if (tid < 2 * IFs) {  // itf partials from padded LDS W_if -> tagged stores
        const int o = tid >> 1, bl = tid & 1;
        const float4* wr = (const float4*)(sm + P1_WIF + o * 68);
        const float4* h4 = (const float4*)(sm + P1_HSL + bl * 64);
        float acc = 0.f;
#pragma unroll 8
        for (int c4 = 0; c4 < 16; ++c4) {
          float4 w = wr[c4]; float4 h = h4[c4];
          acc += w.x * h.x + w.y * h.y + w.z * h.z + w.w * h.w;
        }
        tstore(g_if64 + ((size_t)(b0 + bl) * 8 + jb) * 200 + o, (unsigned)(t + 1), acc);
      }
    }
  } else {
    // ======================= P2: DNC memory for batch b
    const int b = wg - NP1;
    float* SCR = sm + P2_SCR;
    float regL[32], regLT[32];
#pragma unroll
    for (int k = 0; k < 32; ++k) { regL[k] = 0.f; regLT[k] = 0.f; }
    for (int i = tid; i < Nn * 65; i += NT) sm[P2_MEM + i] = 0.f;
    if (tid < 128) { sm[P2_USAGE + tid] = 0.f; sm[P2_RW + tid] = 0.f; }
    if (tid < 256) sm[P2_PREC + tid] = 0.f;   // both parities
    if (tid < IFs) sm[P2_BIF + tid] = b_if[tid];
    __syncthreads();
    // prologue: alloc for t=0 from usage=0 -> ALLOC parity 0
    if (tid < 64) {
      const int li = tid, i0 = 2 * li, i1 = i0 + 1;
      float u0 = sm[P2_USAGE + i0], u1 = sm[P2_USAGE + i1];
      int r0 = 0, r1 = 0;
      for (int jc = 0; jc < 32; ++jc) {
        float4 uj4 = *(const float4*)(sm + P2_USAGE + jc * 4);
#pragma unroll
        for (int e = 0; e < 4; ++e) {
          float uj = (&uj4.x)[e];
          int j = jc * 4 + e;
          r0 += (uj < u0 || (uj == u0 && j < i0)) ? 1 : 0;
          r1 += (uj < u1 || (uj == u1 && j < i1)) ? 1 : 0;
        }
      }
      sm[P2_SS + r0] = u0;
      sm[P2_SS + r1] = u1;
      float s0 = sm[P2_SS + i0], s1 = sm[P2_SS + i1];
      float p = s0 * s1;
#pragma unroll
      for (int off = 1; off < 64; off <<= 1) {
        float v = __shfl_up(p, off, 64);
        if (li >= off) p *= v;
      }
      float E = __shfl_up(p, 1, 64);
      if (li == 0) E = 1.f;
      sm[P2_SCAN + i0] = E * s0;
      sm[P2_SCAN + i1] = E * s0 * s1;
      float ex0 = (r0 > 0) ? sm[P2_SCAN + r0 - 1] : 1.f;
      float ex1 = (r1 > 0) ? sm[P2_SCAN + r1 - 1] : 1.f;
      sm[P2_ALLOC + i0] = (1.f - u0) * ex0;
      sm[P2_ALLOC + i1] = (1.f - u1) * ex1;
    }
    __syncthreads();

    for (int t = 0; t < Tt; ++t) {
      // ---- phase 1: issue itf polls; PRECOMPUTE link sums during the wait
      const u64 *q0 = 0, *q1 = 0, *q2 = 0, *q3 = 0;
      u64 a0 = 0, a1 = 0, a2 = 0, a3 = 0;
      if (tid < 2 * IFs) {
        const int o = tid >> 1, hf = tid & 1;
        q0 = g_if64 + ((size_t)b * 8 + hf * 4) * 200 + o;
        q1 = q0 + 200; q2 = q0 + 400; q3 = q0 + 600;
        a0 = ldrelax(q0); a1 = ldrelax(q1); a2 = ldrelax(q2); a3 = ldrelax(q3);
      }
      float pA, pB, pA2, pB2, pP, pQ;
      {
        const int ws = tid >> 7;
        const float* RWh = sm + P2_RW + ws * 32;
        const float* ALh = sm + P2_ALLOC + (t & 1) * 128 + ws * 32;
        const float* PRh = sm + P2_PREC + (t & 1) * 128 + ws * 32;
        pA = 0.f; pB = 0.f; pA2 = 0.f; pB2 = 0.f; pP = 0.f; pQ = 0.f;
#pragma unroll
        for (int j = 0; j < 32; ++j) {
          float r = RWh[j], a = ALh[j], p = PRh[j];
          float ar = a * r;
          pA += regL[j] * r;
          pB += regL[j] * ar;
          pA2 += regLT[j] * r;
          pB2 += regLT[j] * ar;
          pP += p * r;
          pQ += ar;
        }
      }
      if (tid < 2 * IFs) {
        waitquad(q0, q1, q2, q3, a0, a1, a2, a3, (unsigned)(t + 1));
        float s = tval(a0) + tval(a1) + tval(a2) + tval(a3);
        s += __shfl_xor(s, 1, 64);
        const int o = tid >> 1, hf = tid & 1;
        if (hf == 0) sm[P2_ITF + o] = s + sm[P2_BIF + o];
      }
      __syncthreads();
      // ---- phase 2: wave0 short block (scalars + ww from ALLOC + usage + wwsum)
      float kn_r = 0.f, rstr_r = 0.f, rm0_r = 0.f, rm1_r = 0.f, rm2_r = 0.f;
      if (tid < 64) {
        const int li = tid, i0 = 2 * li, i1 = i0 + 1;
        const float* ALo = sm + P2_ALLOC + (t & 1) * 128;
        float wgag = sigf(sm[P2_ITF + 128]) * sigf(sm[P2_ITF + 129]);
        float rs = sm[P2_ITF + 194];
        rstr_r = (rs > 20.f) ? rs : log1pf(expf(rs));
        float m0 = sm[P2_ITF + 195], m1 = sm[P2_ITF + 196], m2 = sm[P2_ITF + 197];
        float mx = fmaxf(m0, fmaxf(m1, m2));
        float e0 = expf(m0 - mx), e1 = expf(m1 - mx), e2 = expf(m2 - mx);
        float es = e0 + e1 + e2;
        rm0_r = e0 / es; rm1_r = e1 / es; rm2_r = e2 / es;
        float rk = sm[P2_ITF + li];
        sm[P2_ERASE + li] = sigf(rk);
        sm[P2_WVEC + li] = sm[P2_ITF + 64 + li];
        float sq = rk * rk;
#pragma unroll
        for (int off = 32; off > 0; off >>= 1) sq += __shfl_xor(sq, off, 64);
        kn_r = sqrtf(sq) + 1e-8f;
        float u0 = sm[P2_USAGE + i0], u1 = sm[P2_USAGE + i1];
        float w0 = wgag * ALo[i0];
        float w1 = wgag * ALo[i1];
        sm[P2_WW + i0] = w0; sm[P2_WW + i1] = w1;
        sm[P2_USAGE + i0] = u0 + (1.f - u0) * w0;
        sm[P2_USAGE + i1] = u1 + (1.f - u1) * w1;
        float wws = w0 + w1;
#pragma unroll
        for (int off = 32; off > 0; off >>= 1) wws += __shfl_xor(wws, off, 64);
        if (li == 0) sm[P2_SCAL + S_WWSUM] = wws;
      }
      __syncthreads();
      // ---- phase 3: mem+dot+mn (unchanged) + CLOSED-FORM bwp/fwp (O(1))
      {
        const int n = tid & 127, ws = tid >> 7;
        float4 er[4], wv[4], kf[4];
#pragma unroll
        for (int r = 0; r < 4; ++r) {
          er[r] = *(const float4*)(sm + P2_ERASE + ws * 16 + r * 4);
          wv[r] = *(const float4*)(sm + P2_WVEC + ws * 16 + r * 4);
          kf[r] = *(const float4*)(sm + P2_ITF + ws * 16 + r * 4);
        }
        float wwn = sm[P2_WW + n];
        float dotp = 0.f, mnp = 0.f;
        const int base = P2_MEM + n * 65 + ws * 16;
#pragma unroll
        for (int q = 0; q < 16; ++q) {
          float m = sm[base + q];
          float ee = (&er[q >> 2].x)[q & 3];
          float vv = (&wv[q >> 2].x)[q & 3];
          float kk = (&kf[q >> 2].x)[q & 3];
          m = m * (1.f - wwn * ee) + wwn * vv;
          sm[base + q] = m;
          dotp += kk * m;
          mnp += m * m;
        }
        SCR[ws * 128 + n] = dotp;
        SCR[512 + ws * 128 + n] = mnp;
        const int m = n;
        float wgag = sigf(sm[P2_ITF + 128]) * sigf(sm[P2_ITF + 129]);
        float alloc_m = sm[P2_ALLOC + (t & 1) * 128 + m];
        float wwm = wgag * alloc_m;
        float prec_m = sm[P2_PREC + (t & 1) * 128 + m];
        float rw_m = sm[P2_RW + m];
        bool diag = (m >= ws * 32) && (m < ws * 32 + 32);
        float Pc = pP - (diag ? prec_m * rw_m : 0.f);
        float Qc = pQ - (diag ? alloc_m * rw_m : 0.f);
        float bwp = pA * (1.f - wwm) - wgag * pB + wwm * Pc;
        float fwp = pA2 * (1.f - wwm) - wgag * pB2 + prec_m * wgag * Qc;
        SCR[1024 + ws * 128 + m] = bwp;
        SCR[1536 + ws * 128 + m] = fwp;
      }
      __syncthreads();
      // ---- phase 4: softmax + combine + normalize (unchanged)
      if (tid < 64) {
        int i0 = 2 * tid, i1 = i0 + 1;
        float d0 = SCR[i0] + SCR[128 + i0] + SCR[256 + i0] + SCR[384 + i0];
        float d1 = SCR[i1] + SCR[128 + i1] + SCR[256 + i1] + SCR[384 + i1];
        float mn0 = sqrtf(SCR[512 + i0] + SCR[640 + i0] + SCR[768 + i0] + SCR[896 + i0]) + 1e-8f;
        float mn1 = sqrtf(SCR[512 + i1] + SCR[640 + i1] + SCR[768 + i1] + SCR[896 + i1]) + 1e-8f;
        float bw0 = SCR[1024 + i0] + SCR[1152 + i0] + SCR[1280 + i0] + SCR[1408 + i0];
        float bw1 = SCR[1024 + i1] + SCR[1152 + i1] + SCR[1280 + i1] + SCR[1408 + i1];
        float fw0 = SCR[1536 + i0] + SCR[1664 + i0] + SCR[1792 + i0] + SCR[1920 + i0];
        float fw1 = SCR[1536 + i1] + SCR[1664 + i1] + SCR[1792 + i1] + SCR[1920 + i1];
        float q0 = d0 / (kn_r * mn0) * rstr_r;
        float q1 = d1 / (kn_r * mn1) * rstr_r;
        float mx = fmaxf(q0, q1);
#pragma unroll
        for (int off = 32; off > 0; off >>= 1) mx = fmaxf(mx, __shfl_xor(mx, off, 64));
        float e0 = expf(q0 - mx), e1 = expf(q1 - mx);
        float es = e0 + e1;
#pragma unroll
        for (int off = 32; off > 0; off >>= 1) es += __shfl_xor(es, off, 64);
        float wv0 = rm0_r * bw0 + rm1_r * fw0 + rm2_r * (e0 / es) + 1e-8f;
        float wv1 = rm0_r * bw1 + rm1_r * fw1 + rm2_r * (e1 / es) + 1e-8f;
        float wsum = wv0 + wv1;
#pragma unroll
        for (int off = 32; off > 0; off >>= 1) wsum += __shfl_xor(wsum, off, 64);
        sm[P2_RW + i0] = wv0 / wsum;
        sm[P2_RW + i1] = wv1 / wsum;
      }
      __syncthreads();
      // ---- phase 5: rvec partials (unchanged)
      {
        const int w = tid & 63, ns8 = tid >> 6;
        float4 rw4[4];
#pragma unroll
        for (int r = 0; r < 4; ++r)
          rw4[r] = *(const float4*)(sm + P2_RW + ns8 * 16 + r * 4);
        float p = 0.f;
#pragma unroll
        for (int k = 0; k < 16; ++k)
          p += (&rw4[k >> 2].x)[k & 3] * sm[P2_MEM + (ns8 * 16 + k) * 65 + w];
        SCR[ns8 * 64 + w] = p;
      }
      __syncthreads();
      // ---- phase 6 (merged): rvec publish | h gather | alloc | prec
      //      + DEFERRED L/LT state update (all threads, off the rvec chain)
      if (tid < 64) {          // rvec reduce -> tagged store (critical-path exit)
        float r = 0.f;
#pragma unroll
        for (int s2 = 0; s2 < 8; ++s2) r += SCR[s2 * 64 + tid];
        sm[P2_H + 512 + tid] = r;
        tstore(g_rv64 + (size_t)b * Wd + tid, (unsigned)(t + 1), r);
      } else if (tid < 320) {  // tagged h gather — concurrent wait
        const int idx = tid - 64;
        const u64* hsrc = g_h64 + (size_t)(t & 1) * (Bb * Hh) + (size_t)b * Hh;
        const u64* h0 = hsrc + idx * 2;
        const u64* h1 = hsrc + idx * 2 + 1;
        u64 v0 = ldrelax(h0), v1 = ldrelax(h1);
        waitpair(h0, h1, v0, v1, (unsigned)(t + 1));
        sm[P2_H + idx * 2] = tval(v0);
        sm[P2_H + idx * 2 + 1] = tval(v1);
      } else if (tid < 384) {  // next step's alloc from usage(t) -> parity^1
        const int li = tid - 320, i0 = 2 * li, i1 = i0 + 1;
        float u0 = sm[P2_USAGE + i0], u1 = sm[P2_USAGE + i1];
        int r0 = 0, r1 = 0;
        for (int jc = 0; jc < 32; ++jc) {
          float4 uj4 = *(const float4*)(sm + P2_USAGE + jc * 4);
#pragma unroll
          for (int e = 0; e < 4; ++e) {
            float uj = (&uj4.x)[e];
            int j = jc * 4 + e;
            r0 += (uj < u0 || (uj == u0 && j < i0)) ? 1 : 0;
            r1 += (uj < u1 || (uj == u1 && j < i1)) ? 1 : 0;
          }
        }
        sm[P2_SS + r0] = u0;
        sm[P2_SS + r1] = u1;
        float s0 = sm[P2_SS + i0], s1 = sm[P2_SS + i1];
        float p = s0 * s1;
#pragma unroll
        for (int off = 1; off < 64; off <<= 1) {
          float v = __shfl_up(p, off, 64);
          if (li >= off) p *= v;
        }
        float E = __shfl_up(p, 1, 64);
        if (li == 0) E = 1.f;
        sm[P2_SCAN + i0] = E * s0;
        sm[P2_SCAN + i1] = E * s0 * s1;
        float ex0 = (r0 > 0) ? sm[P2_SCAN + r0 - 1] : 1.f;
        float ex1 = (r1 > 0) ? sm[P2_SCAN + r1 - 1] : 1.f;
        float* ALn = sm + P2_ALLOC + ((t + 1) & 1) * 128;
        ALn[i0] = (1.f - u0) * ex0;
        ALn[i1] = (1.f - u1) * ex1;
      } else {                 // prec update -> parity^1 (reads old parity)
        const int n2 = tid - 384;   // 0..127
        float wws = sm[P2_SCAL + S_WWSUM];
        sm[P2_PREC + ((t + 1) & 1) * 128 + n2] =
            (1.f - wws) * sm[P2_PREC + (t & 1) * 128 + n2] + sm[P2_WW + n2];
      }
      {  // deferred link-state update: reads OLD-parity alloc/prec + ITF
        const int m2 = tid & 127, ws2 = tid >> 7;
        float wgag6 = sigf(sm[P2_ITF + 128]) * sigf(sm[P2_ITF + 129]);
        float wwm6 = wgag6 * sm[P2_ALLOC + (t & 1) * 128 + m2];
        float pm = sm[P2_PREC + (t & 1) * 128 + m2];
        const float* ALh = sm + P2_ALLOC + (t & 1) * 128 + ws2 * 32;
        const float* PRh = sm + P2_PREC + (t & 1) * 128 + ws2 * 32;
#pragma unroll
        for (int j = 0; j < 32; ++j) {
          int k = ws2 * 32 + j;
          float wwk = wgag6 * ALh[j];
          float L = regL[j];
          L = (1.f - wwk - wwm6) * L + PRh[j] * wwm6;
          if (k == m2) L = 0.f;
          regL[j] = L;
          float LT = regLT[j];
          LT = (1.f - wwm6 - wwk) * LT + pm * wwk;
          if (k == m2) LT = 0.f;
          regLT[j] = LT;
        }
      }
      __syncthreads();
      // ---- phase 7: out projection (no trailing barrier needed)
      {
        const int o = tid >> 3, seg = tid & 7;
        const float4* wrow = (const float4*)(W_out + (size_t)o * 576) + seg * 18;
        const float4* hb = (const float4*)(sm + P2_H) + seg * 18;
        float p = 0.f;
#pragma unroll
        for (int q = 0; q < 18; ++q) {
          float4 w = wrow[q]; float4 h = hb[q];
          p += w.x * h.x + w.y * h.y + w.z * h.z + w.w * h.w;
        }
        p += __shfl_down(p, 4, 8);
        p += __shfl_down(p, 2, 8);
        p += __shfl_down(p, 1, 8);
        if (seg == 0) out[((size_t)b * Tt + t) * Oo + o] = p + b_out[o];
      }
    }
  }
}

extern "C" void kernel_launch(void* const* d_in, const int* in_sizes, int n_in,
                              void* d_out, int out_size, void* d_ws, size_t ws_size,
                              hipStream_t stream) {
  (void)in_sizes; (void)n_in; (void)d_ws; (void)ws_size; (void)out_size;
  const float* x    = (const float*)d_in[0];
  const float* W_ih = (const float*)d_in[1];
  const float* W_hh = (const float*)d_in[2];
  const float* b_ih = (const float*)d_in[3];
  const float* b_hh = (const float*)d_in[4];
  const float* W_if = (const float*)d_in[5];
  const float* b_if = (const float*)d_in[6];
  const float* W_out = (const float*)d_in[7];
  const float* b_out = (const float*)d_in[8];
  float* out = (float*)d_out;

  dnc_init<<<320, TIN, 0, stream>>>(W_ih, W_hh, b_ih, b_hh);

  hipFuncSetAttribute((const void*)dnc_main,
                      hipFuncAttributeMaxDynamicSharedMemorySize, SMEM_BYTES);

  void* args[] = {(void*)&x, (void*)&W_if, (void*)&b_if,
                  (void*)&W_out, (void*)&b_out, (void*)&out};
  hipLaunchCooperativeKernel((void*)dnc_main, dim3(NWG), dim3(NT), args,
                             SMEM_BYTES, stream);
}

// Round 12
// 863.483 us; speedup vs baseline: 1.3883x; 1.3883x over previous
//
#include <hip/hip_runtime.h>
#include <math.h>

// DNC: B=32,T=64,I=64,O=64,H=512,N=128,W=64,IF=198
// R25 = R23 EXACT (best measured: 797us steady). Final state.
// Session conclusion: the kernel is latency-bound on the 2-MALL-hop/step
// dependency cycle (h -> gates -> itf -> P2 -> rvec). Work-side levers all
// tested and refuted in isolation (R14-R24); HBM 1.6%, VALU 11%, no LDS
// pressure. R24's off-chain link algebra regressed on register cost; revert.
#define Bb 32
#define Tt 64
#define Ii 64
#define Oo 64
#define Hh 512
#define Nn 128
#define Wd 64
#define IFs 198
#define KV 640
#define G4 2048

#define NP1 128          /* 16 bb-groups x 8 jb-slices */
#define NWG 160          /* + 32 P2 wgs */
#define NT 512

// ---- LDS layout (float offsets). P1/P2 blocks overlap (roles fixed per wg).
// P2 block:
#define P2_MEM    0        /* 128*65 = 8320 */
#define P2_H      8320     /* 576 [h|rvec] */
#define P2_SCR    8896     /* 2048 */
#define P2_ITF    10944    /* 224 */
#define P2_ERASE  11168
#define P2_WVEC   11232
#define P2_USAGE  11296
#define P2_PREC   11424
#define P2_RW     11552
#define P2_WW     11680
#define P2_SCAN   11808
#define P2_SS     11936
#define P2_SCAL   12064    /* 16 */
#define P2_BIF    12080    /* 224 */
#define P2_ALLOC  12304    /* 128 (precomputed allocation weights) */
// P1 block (W_if rows padded to 68):
#define P1_WIF    0        /* 198*68 = 13464 */
#define P1_BS     13464    /* 256 */
#define P1_V      13720    /* 640 rows x 2 batches interleaved = 1280 */
#define P1_CC     15016    /* 128 */
#define P1_HSL    15144    /* 128 */
#define P1_PACC   15272    /* 32*65 float4 = 8320 */
#define SMEM_FLOATS 23592  /* 94368 B */
#define SMEM_BYTES (SMEM_FLOATS * 4)

#define S_WWSUM 0

// WT row permutation: rows = [h(512) | x(64) | rvec(64)].
__device__ __align__(16) float g_WT[KV * G4];
__device__ __align__(16) float g_bsum[G4];
typedef unsigned long long u64;
// Tagged handoffs: u64 = (step_tag << 32) | float_bits. Relaxed agent atomics.
__device__ u64 g_h64[2 * Bb * Hh];   // h, step-parity double buffer, tag t+1
__device__ u64 g_rv64[Bb * Wd];      // rvec(t) tag t+1
__device__ u64 g_if64[Bb * 8 * 200]; // itf partials [b][jb(8)][o pad200] tag t+1

__device__ __forceinline__ float sigf(float v) { return 1.f / (1.f + expf(-v)); }

__device__ __forceinline__ u64 ldrelax(const u64* p) {
  return __hip_atomic_load(p, __ATOMIC_RELAXED, __HIP_MEMORY_SCOPE_AGENT);
}
__device__ __forceinline__ void tstore(u64* p, unsigned tag, float v) {
  u64 val = ((u64)tag << 32) | (u64)__float_as_uint(v);
  __hip_atomic_store(p, val, __ATOMIC_RELAXED, __HIP_MEMORY_SCOPE_AGENT);
}
__device__ __forceinline__ float tval(u64 v) {
  return __uint_as_float((unsigned)(v & 0xffffffffu));
}
// Staged-backoff sleep: 2 fast retries, then long sleep to cut poll-storm
// traffic at the MALL (s_sleep arg must be a compile-time constant).
__device__ __forceinline__ void bsleep(int k) {
  if (k < 2) __builtin_amdgcn_s_sleep(1);
  else       __builtin_amdgcn_s_sleep(8);
}
// Combined concurrent polls (R19): reload ALL invalid slots per iteration so
// the independent loads overlap in flight; staged backoff between rounds.
__device__ __forceinline__ void waitpair(const u64* p0, const u64* p1,
                                         u64& v0, u64& v1, unsigned tag) {
  int k = 0;
  while (((unsigned)(v0 >> 32)) != tag || ((unsigned)(v1 >> 32)) != tag) {
    bsleep(k); ++k;
    v0 = ldrelax(p0);
    v1 = ldrelax(p1);
  }
}
__device__ __forceinline__ void waitquad(const u64* p0, const u64* p1,
                                         const u64* p2, const u64* p3,
                                         u64& v0, u64& v1, u64& v2, u64& v3,
                                         unsigned tag) {
  int k = 0;
  while (((unsigned)(v0 >> 32)) != tag || ((unsigned)(v1 >> 32)) != tag ||
         ((unsigned)(v2 >> 32)) != tag || ((unsigned)(v3 >> 32)) != tag) {
    bsleep(k); ++k;
    v0 = ldrelax(p0);
    v1 = ldrelax(p1);
    v2 = ldrelax(p2);
    v3 = ldrelax(p3);
  }
}

#define TIN 512
__global__ __launch_bounds__(TIN) void dnc_init(const float* __restrict__ W_ih,
                                                const float* __restrict__ W_hh,
                                                const float* __restrict__ b_ih,
                                                const float* __restrict__ b_hh) {
  __shared__ float tile[64][65];
  const int tid = threadIdx.x;
  int i0 = blockIdx.x * blockDim.x + tid;
  int st = gridDim.x * blockDim.x;
  for (int idx = i0; idx < G4; idx += st) g_bsum[idx] = b_ih[idx] + b_hh[idx];
  for (int idx = i0; idx < 2 * Bb * Hh; idx += st) g_h64[idx] = 0ull;
  for (int idx = i0; idx < Bb * Wd; idx += st) g_rv64[idx] = 0ull;
  for (int idx = i0; idx < Bb * 8 * 200; idx += st) g_if64[idx] = 0ull;

  for (int tileId = blockIdx.x; tileId < 320; tileId += gridDim.x) {
    int tc = tileId >> 5, tj = tileId & 31;
    for (int k = tid; k < 64 * 64; k += TIN) {
      int r = k >> 6, cl = k & 63;
      int j = tj * 64 + r, c = tc * 64 + cl;
      tile[r][cl] = (c < 128) ? W_ih[j * 128 + c] : W_hh[j * 512 + (c - 128)];
    }
    __syncthreads();
    for (int k = tid; k < 64 * 64; k += TIN) {
      int cl = k >> 6, rjj = k & 63;
      int c = tc * 64 + cl;
      // rows: h u -> u ; x c -> 512+c ; rvec -> 576+(c-64)  (== 512+c)
      int rp = (c < 128) ? (512 + c) : (c - 128);
      g_WT[(size_t)rp * G4 + tj * 64 + rjj] = tile[rjj][cl];
    }
    __syncthreads();
  }
}

__global__ __launch_bounds__(NT) void dnc_main(const float* __restrict__ x,
                                               const float* __restrict__ W_if,
                                               const float* __restrict__ b_if,
                                               const float* __restrict__ W_out,
                                               const float* __restrict__ b_out,
                                               float* __restrict__ out) {
  extern __shared__ float sm[];
  const int tid = threadIdx.x;
  const int wg = blockIdx.x;

  if (wg < NP1) {
    // ======================= P1: gates GEMV + fused LSTM + itf partials
    const int jb = wg & 7;
    const int bb = wg >> 3;
    const int b0 = bb * 2;
    for (int i = tid; i < IFs * 64; i += NT) {
      int o = i >> 6, c = i & 63;
      sm[P1_WIF + o * 68 + c] = W_if[(size_t)o * Hh + jb * 64 + c];
    }
    if (tid < 64) {
      int gq = tid >> 4, m = tid & 15;
      ((float4*)(sm + P1_BS))[tid] = ((const float4*)g_bsum)[gq * 128 + jb * 16 + m];
    }
    if (tid < 128) sm[P1_CC + tid] = 0.f;
    __syncthreads();

    for (int t = 0; t < Tt; ++t) {
      {  // stage h(t-1) + x, batch-interleaved [row][bl] — concurrent wait
        const u64* hsrc = g_h64 + (size_t)((t + 1) & 1) * (Bb * Hh);
        const int u = tid;
        const u64* a0 = hsrc + (size_t)b0 * Hh + u;
        const u64* a1 = hsrc + (size_t)(b0 + 1) * Hh + u;
        u64 v0 = ldrelax(a0), v1 = ldrelax(a1);
        waitpair(a0, a1, v0, v1, (unsigned)t);
        float2 hh;
        hh.x = tval(v0);
        hh.y = tval(v1);
        *(float2*)(sm + P1_V + u * 2) = hh;
        if (tid < 128) {
          const int bl2 = tid >> 6, i = tid & 63;
          float xv = x[((size_t)(b0 + bl2) * Tt + t) * Ii + i];
          sm[P1_V + (512 + i) * 2 + bl2] = xv;
        }
      }
      __syncthreads();

      {  // GEMV: 640 rows split 16 ways; each weight loaded once.
        const int fg = tid & 31, ks = tid >> 5;  // ks 0..15, rows ks*40..+39
        const int fcolA = ((fg >> 4) * 128) + jb * 16 + (fg & 15);  // gates 0,1
        const float* v2 = sm + P1_V + ks * 80;
        const float4* wpA = (const float4*)g_WT + (size_t)(ks * 40) * 512 + fcolA;
        if (ks >= 14) {  // wave 7 owns rvec rows 576..639 — concurrent wait
          const int j = tid & 63;
          const u64* r0 = g_rv64 + (size_t)b0 * Wd + j;
          const u64* r1 = g_rv64 + (size_t)(b0 + 1) * Wd + j;
          u64 u0 = ldrelax(r0), u1 = ldrelax(r1);
          waitpair(r0, r1, u0, u1, (unsigned)t);
          float2 rv;
          rv.x = tval(u0);
          rv.y = tval(u1);
          *(float2*)(sm + P1_V + (576 + j) * 2) = rv;  // same-wave write->read
        }
        float4 aA0 = {0.f, 0.f, 0.f, 0.f}, aA1 = {0.f, 0.f, 0.f, 0.f};
        float4 aB0 = {0.f, 0.f, 0.f, 0.f}, aB1 = {0.f, 0.f, 0.f, 0.f};
#pragma unroll 4
        for (int r = 0; r < 40; ++r) {
          float4 wA = wpA[(size_t)r * 512];
          float4 wB = wpA[(size_t)r * 512 + 256];      // gates 2,3
          float2 vv = *(const float2*)(v2 + r * 2);
          aA0.x += wA.x * vv.x; aA0.y += wA.y * vv.x; aA0.z += wA.z * vv.x; aA0.w += wA.w * vv.x;
          aA1.x += wA.x * vv.y; aA1.y += wA.y * vv.y; aA1.z += wA.z * vv.y; aA1.w += wA.w * vv.y;
          aB0.x += wB.x * vv.x; aB0.y += wB.y * vv.x; aB0.z += wB.z * vv.x; aB0.w += wB.w * vv.x;
          aB1.x += wB.x * vv.y; aB1.y += wB.y * vv.y; aB1.z += wB.z * vv.y; aB1.w += wB.w * vv.y;
        }
        float4* pacc = (float4*)(sm + P1_PACC);
        pacc[(ks * 2 + 0) * 65 + fg] = aA0;
        pacc[(ks * 2 + 1) * 65 + fg] = aA1;
        pacc[(ks * 2 + 0) * 65 + fg + 32] = aB0;
        pacc[(ks * 2 + 1) * 65 + fg + 32] = aB1;
      }
      __syncthreads();
      if (tid < 128) {  // fused K-reduce (16 partials) + LSTM; h published tagged
        const int bl = tid >> 6, l = tid & 63;
        const float* pb = sm + P1_PACC + bl * 260 + l;
        float gv0 = 0.f, gv1 = 0.f, gv2 = 0.f, gv3 = 0.f;
#pragma unroll
        for (int ks = 0; ks < 16; ++ks) {
          const float* pk = pb + ks * 520;
          gv0 += pk[0];
          gv1 += pk[64];
          gv2 += pk[128];
          gv3 += pk[192];
        }
        float ig = gv0 + sm[P1_BS + l];
        float fg = gv1 + sm[P1_BS + 64 + l];
        float gg = gv2 + sm[P1_BS + 128 + l];
        float og = gv3 + sm[P1_BS + 192 + l];
        float co = sm[P1_CC + bl * 64 + l];
        float cn = sigf(fg) * co + sigf(ig) * tanhf(gg);
        float hn = sigf(og) * tanhf(cn);
        sm[P1_CC + bl * 64 + l] = cn;
        sm[P1_HSL + bl * 64 + l] = hn;
        tstore(g_h64 + (size_t)(t & 1) * (Bb * Hh) + (size_t)(b0 + bl) * Hh + jb * 64 + l,
               (unsigned)(t + 1), hn);
      }
      __syncthreads();
      if (tid < 2 * IFs) {  // itf partials from padded LDS W_if -> tagged stores
        const int o = tid >> 1, bl = tid & 1;
        const float4* wr = (const float4*)(sm + P1_WIF + o * 68);
        const float4* h4 = (const float4*)(sm + P1_HSL + bl * 64);
        float acc = 0.f;
#pragma unroll 8
        for (int c4 = 0; c4 < 16; ++c4) {
          float4 w = wr[c4]; float4 h = h4[c4];
          acc += w.x * h.x + w.y * h.y + w.z * h.z + w.w * h.w;
        }
        tstore(g_if64 + ((size_t)(b0 + bl) * 8 + jb) * 200 + o, (unsigned)(t + 1), acc);
      }
    }
  } else {
    // ======================= P2: DNC memory for batch b — 6-barrier structure
    const int b = wg - NP1;
    float* SCR = sm + P2_SCR;
    float regL[32], regLT[32];
#pragma unroll
    for (int k = 0; k < 32; ++k) { regL[k] = 0.f; regLT[k] = 0.f; }
    for (int i = tid; i < Nn * 65; i += NT) sm[P2_MEM + i] = 0.f;
    if (tid < 128) { sm[P2_USAGE + tid] = 0.f; sm[P2_PREC + tid] = 0.f; sm[P2_RW + tid] = 0.f; }
    if (tid < IFs) sm[P2_BIF + tid] = b_if[tid];
    __syncthreads();
    // prologue: alloc for t=0 from usage=0
    if (tid < 64) {
      const int li = tid, i0 = 2 * li, i1 = i0 + 1;
      float u0 = sm[P2_USAGE + i0], u1 = sm[P2_USAGE + i1];
      int r0 = 0, r1 = 0;
      for (int jc = 0; jc < 32; ++jc) {
        float4 uj4 = *(const float4*)(sm + P2_USAGE + jc * 4);
#pragma unroll
        for (int e = 0; e < 4; ++e) {
          float uj = (&uj4.x)[e];
          int j = jc * 4 + e;
          r0 += (uj < u0 || (uj == u0 && j < i0)) ? 1 : 0;
          r1 += (uj < u1 || (uj == u1 && j < i1)) ? 1 : 0;
        }
      }
      sm[P2_SS + r0] = u0;
      sm[P2_SS + r1] = u1;
      float s0 = sm[P2_SS + i0], s1 = sm[P2_SS + i1];
      float p = s0 * s1;
#pragma unroll
      for (int off = 1; off < 64; off <<= 1) {
        float v = __shfl_up(p, off, 64);
        if (li >= off) p *= v;
      }
      float E = __shfl_up(p, 1, 64);
      if (li == 0) E = 1.f;
      sm[P2_SCAN + i0] = E * s0;
      sm[P2_SCAN + i1] = E * s0 * s1;
      float ex0 = (r0 > 0) ? sm[P2_SCAN + r0 - 1] : 1.f;
      float ex1 = (r1 > 0) ? sm[P2_SCAN + r1 - 1] : 1.f;
      sm[P2_ALLOC + i0] = (1.f - u0) * ex0;
      sm[P2_ALLOC + i1] = (1.f - u1) * ex1;
    }
    __syncthreads();

    for (int t = 0; t < Tt; ++t) {
      // ---- phase 1: tagged itf gather — concurrent quad wait
      if (tid < 2 * IFs) {
        const int o = tid >> 1, hf = tid & 1;
        const u64* src = g_if64 + ((size_t)b * 8 + hf * 4) * 200 + o;
        u64 a0 = ldrelax(src), a1 = ldrelax(src + 200),
            a2 = ldrelax(src + 400), a3 = ldrelax(src + 600);
        waitquad(src, src + 200, src + 400, src + 600, a0, a1, a2, a3,
                 (unsigned)(t + 1));
        float s = tval(a0) + tval(a1) + tval(a2) + tval(a3);
        s += __shfl_xor(s, 1, 64);
        if (hf == 0) sm[P2_ITF + o] = s + sm[P2_BIF + o];
      }
      __syncthreads();
      // ---- phase 2: wave0 short block (scalars + ww from ALLOC + usage + wwsum)
      float kn_r = 0.f, rstr_r = 0.f, rm0_r = 0.f, rm1_r = 0.f, rm2_r = 0.f;
      if (tid < 64) {
        const int li = tid, i0 = 2 * li, i1 = i0 + 1;
        float wgag = sigf(sm[P2_ITF + 128]) * sigf(sm[P2_ITF + 129]);
        float rs = sm[P2_ITF + 194];
        rstr_r = (rs > 20.f) ? rs : log1pf(expf(rs));
        float m0 = sm[P2_ITF + 195], m1 = sm[P2_ITF + 196], m2 = sm[P2_ITF + 197];
        float mx = fmaxf(m0, fmaxf(m1, m2));
        float e0 = expf(m0 - mx), e1 = expf(m1 - mx), e2 = expf(m2 - mx);
        float es = e0 + e1 + e2;
        rm0_r = e0 / es; rm1_r = e1 / es; rm2_r = e2 / es;
        float rk = sm[P2_ITF + li];
        sm[P2_ERASE + li] = sigf(rk);
        sm[P2_WVEC + li] = sm[P2_ITF + 64 + li];
        float sq = rk * rk;
#pragma unroll
        for (int off = 32; off > 0; off >>= 1) sq += __shfl_xor(sq, off, 64);
        kn_r = sqrtf(sq) + 1e-8f;
        float u0 = sm[P2_USAGE + i0], u1 = sm[P2_USAGE + i1];
        float w0 = wgag * sm[P2_ALLOC + i0];
        float w1 = wgag * sm[P2_ALLOC + i1];
        sm[P2_WW + i0] = w0; sm[P2_WW + i1] = w1;
        sm[P2_USAGE + i0] = u0 + (1.f - u0) * w0;
        sm[P2_USAGE + i1] = u1 + (1.f - u1) * w1;
        float wws = w0 + w1;
#pragma unroll
        for (int off = 32; off > 0; off >>= 1) wws += __shfl_xor(wws, off, 64);
        if (li == 0) sm[P2_SCAL + S_WWSUM] = wws;
      }
      __syncthreads();
      // ---- phase 3: pass1 (fused mem+dot+mn + register link + bw/fw partials)
      {
        const int n = tid & 127, ws = tid >> 7;
        float4 er[4], wv[4], kf[4];
#pragma unroll
        for (int r = 0; r < 4; ++r) {
          er[r] = *(const float4*)(sm + P2_ERASE + ws * 16 + r * 4);
          wv[r] = *(const float4*)(sm + P2_WVEC + ws * 16 + r * 4);
          kf[r] = *(const float4*)(sm + P2_ITF + ws * 16 + r * 4);
        }
        float wwn = sm[P2_WW + n];
        float dotp = 0.f, mnp = 0.f;
        const int base = P2_MEM + n * 65 + ws * 16;
#pragma unroll
        for (int q = 0; q < 16; ++q) {
          float m = sm[base + q];
          float ee = (&er[q >> 2].x)[q & 3];
          float vv = (&wv[q >> 2].x)[q & 3];
          float kk = (&kf[q >> 2].x)[q & 3];
          m = m * (1.f - wwn * ee) + wwn * vv;
          sm[base + q] = m;
          dotp += kk * m;
          mnp += m * m;
        }
        SCR[ws * 128 + n] = dotp;
        SCR[512 + ws * 128 + n] = mnp;
        const int m = n, ns = ws;
        float wwm = wwn;
        float prn = sm[P2_PREC + m];
        float bwp = 0.f, fwp = 0.f;
#pragma unroll
        for (int kq = 0; kq < 8; ++kq) {
          float4 ww4 = *(const float4*)(sm + P2_WW + ns * 32 + kq * 4);
          float4 pr4 = *(const float4*)(sm + P2_PREC + ns * 32 + kq * 4);
          float4 rw4 = *(const float4*)(sm + P2_RW + ns * 32 + kq * 4);
#pragma unroll
          for (int e = 0; e < 4; ++e) {
            int k = kq * 4 + e;
            int nn = ns * 32 + k;
            float wwo = (&ww4.x)[e];
            float pro = (&pr4.x)[e];
            float rwo = (&rw4.x)[e];
            float L = regL[k];
            L = (1.f - wwo - wwm) * L + pro * wwm;
            if (nn == m) L = 0.f;
            regL[k] = L;
            bwp += L * rwo;
            float LT = regLT[k];
            LT = (1.f - wwm - wwo) * LT + prn * wwo;
            if (nn == m) LT = 0.f;
            regLT[k] = LT;
            fwp += LT * rwo;
          }
        }
        SCR[1024 + ns * 128 + m] = bwp;
        SCR[1536 + ns * 128 + m] = fwp;
      }
      __syncthreads();
      // ---- phase 4: softmax + combine + normalize (pass2 FUSED: read partials)
      if (tid < 64) {
        int i0 = 2 * tid, i1 = i0 + 1;
        float d0 = SCR[i0] + SCR[128 + i0] + SCR[256 + i0] + SCR[384 + i0];
        float d1 = SCR[i1] + SCR[128 + i1] + SCR[256 + i1] + SCR[384 + i1];
        float mn0 = sqrtf(SCR[512 + i0] + SCR[640 + i0] + SCR[768 + i0] + SCR[896 + i0]) + 1e-8f;
        float mn1 = sqrtf(SCR[512 + i1] + SCR[640 + i1] + SCR[768 + i1] + SCR[896 + i1]) + 1e-8f;
        float bw0 = SCR[1024 + i0] + SCR[1152 + i0] + SCR[1280 + i0] + SCR[1408 + i0];
        float bw1 = SCR[1024 + i1] + SCR[1152 + i1] + SCR[1280 + i1] + SCR[1408 + i1];
        float fw0 = SCR[1536 + i0] + SCR[1664 + i0] + SCR[1792 + i0] + SCR[1920 + i0];
        float fw1 = SCR[1536 + i1] + SCR[1664 + i1] + SCR[1792 + i1] + SCR[1920 + i1];
        float q0 = d0 / (kn_r * mn0) * rstr_r;
        float q1 = d1 / (kn_r * mn1) * rstr_r;
        float mx = fmaxf(q0, q1);
#pragma unroll
        for (int off = 32; off > 0; off >>= 1) mx = fmaxf(mx, __shfl_xor(mx, off, 64));
        float e0 = expf(q0 - mx), e1 = expf(q1 - mx);
        float es = e0 + e1;
#pragma unroll
        for (int off = 32; off > 0; off >>= 1) es += __shfl_xor(es, off, 64);
        float wv0 = rm0_r * bw0 + rm1_r * fw0 + rm2_r * (e0 / es) + 1e-8f;
        float wv1 = rm0_r * bw1 + rm1_r * fw1 + rm2_r * (e1 / es) + 1e-8f;
        float wsum = wv0 + wv1;
#pragma unroll
        for (int off = 32; off > 0; off >>= 1) wsum += __shfl_xor(wsum, off, 64);
        sm[P2_RW + i0] = wv0 / wsum;
        sm[P2_RW + i1] = wv1 / wsum;
      }
      __syncthreads();
      // ---- phase 5: rvec partials
      {
        const int w = tid & 63, ns8 = tid >> 6;
        float4 rw4[4];
#pragma unroll
        for (int r = 0; r < 4; ++r)
          rw4[r] = *(const float4*)(sm + P2_RW + ns8 * 16 + r * 4);
        float p = 0.f;
#pragma unroll
        for (int k = 0; k < 16; ++k)
          p += (&rw4[k >> 2].x)[k & 3] * sm[P2_MEM + (ns8 * 16 + k) * 65 + w];
        SCR[ns8 * 64 + w] = p;
      }
      __syncthreads();
      // ---- phase 6 (merged): rvec reduce+publish | h gather | alloc | prec
      if (tid < 64) {          // rvec reduce -> tagged store (critical-path exit)
        float r = 0.f;
#pragma unroll
        for (int s2 = 0; s2 < 8; ++s2) r += SCR[s2 * 64 + tid];
        sm[P2_H + 512 + tid] = r;
        tstore(g_rv64 + (size_t)b * Wd + tid, (unsigned)(t + 1), r);
      } else if (tid < 320) {  // tagged h gather — concurrent wait
        const int idx = tid - 64;
        const u64* hsrc = g_h64 + (size_t)(t & 1) * (Bb * Hh) + (size_t)b * Hh;
        const u64* a0 = hsrc + idx * 2;
        const u64* a1 = hsrc + idx * 2 + 1;
        u64 v0 = ldrelax(a0), v1 = ldrelax(a1);
        waitpair(a0, a1, v0, v1, (unsigned)(t + 1));
        sm[P2_H + idx * 2] = tval(v0);
        sm[P2_H + idx * 2 + 1] = tval(v1);
      } else if (tid < 384) {  // next step's alloc from usage(t) (wave 5)
        const int li = tid - 320, i0 = 2 * li, i1 = i0 + 1;
        float u0 = sm[P2_USAGE + i0], u1 = sm[P2_USAGE + i1];
        int r0 = 0, r1 = 0;
        for (int jc = 0; jc < 32; ++jc) {
          float4 uj4 = *(const float4*)(sm + P2_USAGE + jc * 4);
#pragma unroll
          for (int e = 0; e < 4; ++e) {
            float uj = (&uj4.x)[e];
            int j = jc * 4 + e;
            r0 += (uj < u0 || (uj == u0 && j < i0)) ? 1 : 0;
            r1 += (uj < u1 || (uj == u1 && j < i1)) ? 1 : 0;
          }
        }
        sm[P2_SS + r0] = u0;
        sm[P2_SS + r1] = u1;
        float s0 = sm[P2_SS + i0], s1 = sm[P2_SS + i1];
        float p = s0 * s1;
#pragma unroll
        for (int off = 1; off < 64; off <<= 1) {
          float v = __shfl_up(p, off, 64);
          if (li >= off) p *= v;
        }
        float E = __shfl_up(p, 1, 64);
        if (li == 0) E = 1.f;
        sm[P2_SCAN + i0] = E * s0;
        sm[P2_SCAN + i1] = E * s0 * s1;
        float ex0 = (r0 > 0) ? sm[P2_SCAN + r0 - 1] : 1.f;
        float ex1 = (r1 > 0) ? sm[P2_SCAN + r1 - 1] : 1.f;
        sm[P2_ALLOC + i0] = (1.f - u0) * ex0;
        sm[P2_ALLOC + i1] = (1.f - u1) * ex1;
      } else {                 // prec update (hoisted from old pass2)
        const int n = tid - 384;   // 0..127
        float wws = sm[P2_SCAL + S_WWSUM];
        sm[P2_PREC + n] = (1.f - wws) * sm[P2_PREC + n] + sm[P2_WW + n];
      }
      __syncthreads();
      // ---- phase 7: out projection (no trailing barrier needed)
      {
        const int o = tid >> 3, seg = tid & 7;
        const float4* wrow = (const float4*)(W_out + (size_t)o * 576) + seg * 18;
        const float4* hb = (const float4*)(sm + P2_H) + seg * 18;
        float p = 0.f;
#pragma unroll
        for (int q = 0; q < 18; ++q) {
          float4 w = wrow[q]; float4 h = hb[q];
          p += w.x * h.x + w.y * h.y + w.z * h.z + w.w * h.w;
        }
        p += __shfl_down(p, 4, 8);
        p += __shfl_down(p, 2, 8);
        p += __shfl_down(p, 1, 8);
        if (seg == 0) out[((size_t)b * Tt + t) * Oo + o] = p + b_out[o];
      }
    }
  }
}

extern "C" void kernel_launch(void* const* d_in, const int* in_sizes, int n_in,
                              void* d_out, int out_size, void* d_ws, size_t ws_size,
                              hipStream_t stream) {
  (void)in_sizes; (void)n_in; (void)d_ws; (void)ws_size; (void)out_size;
  const float* x    = (const float*)d_in[0];
  const float* W_ih = (const float*)d_in[1];
  const float* W_hh = (const float*)d_in[2];
  const float* b_ih = (const float*)d_in[3];
  const float* b_hh = (const float*)d_in[4];
  const float* W_if = (const float*)d_in[5];
  const float* b_if = (const float*)d_in[6];
  const float* W_out = (const float*)d_in[7];
  const float* b_out = (const float*)d_in[8];
  float* out = (float*)d_out;

  dnc_init<<<320, TIN, 0, stream>>>(W_ih, W_hh, b_ih, b_hh);

  hipFuncSetAttribute((const void*)dnc_main,
                      hipFuncAttributeMaxDynamicSharedMemorySize, SMEM_BYTES);

  void* args[] = {(void*)&x, (void*)&W_if, (void*)&b_if,
                  (void*)&W_out, (void*)&b_out, (void*)&out};
  hipLaunchCooperativeKernel((void*)dnc_main, dim3(NWG), dim3(NT), args,
                             SMEM_BYTES, stream);
}